// Round 1
// baseline (57.532 us; speedup 1.0000x reference)
//
#include <hip/hip_runtime.h>

#define KK 5
#define RR 2
#define SS 2
#define N_ 2
#define C_ 256
#define H_ 128
#define W_ 128
#define H2 (H_*SS)   // 256
#define W2 (W_*SS)   // 256
#define TH 16
#define TW 16
#define CCHUNK 32
#define PH (TH + 2*RR)   // 20
#define PW (TW + 2*RR)   // 20

__global__ __launch_bounds__(256) void carafe_kernel(
    const float* __restrict__ feat,
    const float* __restrict__ masks,
    float* __restrict__ out)
{
    __shared__ float patch[PH * PW];

    const int tid = threadIdx.x;
    const int tx = tid & 15;
    const int ty = tid >> 4;
    const int bx = blockIdx.x & 7;    // W_/TW = 8
    const int by = blockIdx.x >> 3;   // H_/TH = 8
    const int c0 = blockIdx.y * CCHUNK;
    const int n  = blockIdx.z;

    const int i0 = by * TH + ty;      // source row
    const int j0 = bx * TW + tx;      // source col

    // Load all 25 * 2x2 mask values for this source pixel into registers.
    // masks[n][k][2*i0+a][2*j0 + b], float2 along b -> coalesced.
    float m[KK * KK][SS][SS];
    const float* mbase = masks + (size_t)n * (KK * KK) * (size_t)(H2 * W2);
    #pragma unroll
    for (int k = 0; k < KK * KK; ++k) {
        #pragma unroll
        for (int a = 0; a < SS; ++a) {
            const float2 mv = *reinterpret_cast<const float2*>(
                mbase + ((size_t)k * H2 + (2 * i0 + a)) * W2 + 2 * j0);
            m[k][a][0] = mv.x;
            m[k][a][1] = mv.y;
        }
    }

    const int gy0 = by * TH - RR;
    const int gx0 = bx * TW - RR;

    for (int cc = 0; cc < CCHUNK; ++cc) {
        const int c = c0 + cc;
        const float* fbase = feat + (size_t)(n * C_ + c) * (H_ * W_);

        __syncthreads();   // protect previous iteration's patch reads
        for (int idx = tid; idx < PH * PW; idx += 256) {
            const int py = idx / PW;
            const int px = idx - py * PW;
            const int gy = gy0 + py;
            const int gx = gx0 + px;
            float v = 0.f;
            if ((unsigned)gy < (unsigned)H_ && (unsigned)gx < (unsigned)W_)
                v = fbase[gy * W_ + gx];
            patch[idx] = v;
        }
        __syncthreads();

        float acc00 = 0.f, acc01 = 0.f, acc10 = 0.f, acc11 = 0.f;
        #pragma unroll
        for (int dy = 0; dy < KK; ++dy) {
            #pragma unroll
            for (int dx = 0; dx < KK; ++dx) {
                const float v = patch[(ty + dy) * PW + (tx + dx)];
                const int k = dy * KK + dx;
                acc00 += v * m[k][0][0];
                acc01 += v * m[k][0][1];
                acc10 += v * m[k][1][0];
                acc11 += v * m[k][1][1];
            }
        }

        float* obase = out + ((size_t)(n * C_ + c) * H2 + (size_t)(2 * i0)) * W2 + 2 * j0;
        *reinterpret_cast<float2*>(obase)      = make_float2(acc00, acc01);
        *reinterpret_cast<float2*>(obase + W2) = make_float2(acc10, acc11);
    }
}

extern "C" void kernel_launch(void* const* d_in, const int* in_sizes, int n_in,
                              void* d_out, int out_size, void* d_ws, size_t ws_size,
                              hipStream_t stream) {
    const float* feat  = (const float*)d_in[0];
    const float* masks = (const float*)d_in[1];
    float* out = (float*)d_out;

    dim3 grid(( W_ / TW) * (H_ / TH),  // 64 spatial tiles
              C_ / CCHUNK,             // 8 channel chunks
              N_);                     // 2 batch
    dim3 block(256);
    carafe_kernel<<<grid, block, 0, stream>>>(feat, masks, out);
}